// Round 3
// baseline (48.353 us; speedup 1.0000x reference)
//
#include <hip/hip_runtime.h>
#include <hip/hip_bf16.h>
#include <math.h>

// Chamfer 2D, B=8, N=4096, fp32.
// Stage1: per (dir,n,c) block, min over a j-chunk of (s_j - 2 x.y_j).
//   Database points read via wave-uniform s_load (no LDS at all);
//   inner loop: v_pk_fma_f32 (2 queries/instr) + v_min3_f32 (2 j's/min).
// Stage2: min over c, add |q|^2, sqrt, block-sum. Stage3: final tree sum.

typedef float f32x2 __attribute__((ext_vector_type(2)));

#define B 8
#define N 4096
#define NJ 64
#define JC (N / NJ)      // 64 j's per stage1 block
#define S1B 128          // stage1 block size (2 waves)
#define TX 32            // queries per thread: S1B*TX = 4096
#define NT 16            // i-tiles in stage2
#define S2B 256

// partial layout: [c][dir][n][i]
__global__ __launch_bounds__(S1B, 2) void chamfer_stage1(
    const float2* __restrict__ P1, const float2* __restrict__ P2,
    float* __restrict__ partial) {
  int b = blockIdx.x;
  int c = b % NJ; b /= NJ;
  int n = b % B;
  int dir = b / B;

  const float2* __restrict__ Q = dir ? P2 : P1;
  const float2* __restrict__ D = dir ? P1 : P2;
  const float2* __restrict__ db = D + n * N + c * JC;  // wave-uniform

  f32x2 qx[TX / 2], qy[TX / 2];
  float m[TX];
  const float2* qbase = Q + n * N + threadIdx.x;
#pragma unroll
  for (int p = 0; p < TX / 2; ++p) {
    float2 q0 = qbase[(2 * p) * S1B];
    float2 q1 = qbase[(2 * p + 1) * S1B];
    qx[p] = (f32x2){q0.x, q1.x};
    qy[p] = (f32x2){q0.y, q1.y};
    m[2 * p] = INFINITY;
    m[2 * p + 1] = INFINITY;
  }

#pragma unroll 4
  for (int j = 0; j < JC; j += 2) {
    float2 p0 = db[j];        // uniform -> s_load, scalar cache
    float2 p1 = db[j + 1];
    float ax0f = -2.f * p0.x, ay0f = -2.f * p0.y;
    float s0f = fmaf(p0.x, p0.x, p0.y * p0.y);
    float ax1f = -2.f * p1.x, ay1f = -2.f * p1.y;
    float s1f = fmaf(p1.x, p1.x, p1.y * p1.y);
    f32x2 ax0 = {ax0f, ax0f}, ay0 = {ay0f, ay0f}, ss0 = {s0f, s0f};
    f32x2 ax1 = {ax1f, ax1f}, ay1 = {ay1f, ay1f}, ss1 = {s1f, s1f};
#pragma unroll
    for (int p = 0; p < TX / 2; ++p) {
      f32x2 u0, t0, u1, t1;
      asm("v_pk_fma_f32 %0, %1, %2, %3" : "=v"(u0) : "v"(qy[p]), "v"(ay0), "v"(ss0));
      asm("v_pk_fma_f32 %0, %1, %2, %3" : "=v"(t0) : "v"(qx[p]), "v"(ax0), "v"(u0));
      asm("v_pk_fma_f32 %0, %1, %2, %3" : "=v"(u1) : "v"(qy[p]), "v"(ay1), "v"(ss1));
      asm("v_pk_fma_f32 %0, %1, %2, %3" : "=v"(t1) : "v"(qx[p]), "v"(ax1), "v"(u1));
      asm("v_min3_f32 %0, %0, %1, %2" : "+v"(m[2 * p])     : "v"(t0.x), "v"(t1.x));
      asm("v_min3_f32 %0, %0, %1, %2" : "+v"(m[2 * p + 1]) : "v"(t0.y), "v"(t1.y));
    }
  }

  float* __restrict__ dst =
      partial + (((size_t)c * 2 + dir) * B + n) * N + threadIdx.x;
#pragma unroll
  for (int k = 0; k < TX; ++k) dst[k * S1B] = m[k];
}

// grid: 2*B*NT blocks; min over c, add |q|^2, sqrt, block-sum.
__global__ __launch_bounds__(S2B) void chamfer_stage2(
    const float2* __restrict__ P1, const float2* __restrict__ P2,
    const float* __restrict__ partial, float* __restrict__ bs) {
  int b = blockIdx.x;
  int t = b % NT; b /= NT;
  int n = b % B;
  int dir = b / B;

  const float2* __restrict__ Q = dir ? P2 : P1;
  int i = t * S2B + threadIdx.x;

  float m = INFINITY;
  const float* __restrict__ pbase = partial + ((size_t)dir * B + n) * N + i;
#pragma unroll 8
  for (int c = 0; c < NJ; ++c)
    m = fminf(m, pbase[(size_t)c * 2 * B * N]);

  float2 q = Q[n * N + i];
  float d2 = m + fmaf(q.x, q.x, q.y * q.y);
  float sum = sqrtf(fmaxf(d2, 0.0f));

  __shared__ float red[S2B];
  red[threadIdx.x] = sum;
  __syncthreads();
  for (int s = S2B / 2; s > 0; s >>= 1) {
    if (threadIdx.x < s) red[threadIdx.x] += red[threadIdx.x + s];
    __syncthreads();
  }
  if (threadIdx.x == 0) bs[(dir * B + n) * NT + t] = red[0];
}

// grid: B blocks x 64 threads; reduce 2*NT=32 sums per n.
__global__ __launch_bounds__(64) void chamfer_stage3(
    const float* __restrict__ bs, float* __restrict__ out) {
  int n = blockIdx.x;
  int lane = threadIdx.x;
  float v = 0.0f;
  if (lane < 2 * NT) {
    int dir = lane / NT, t = lane % NT;
    v = bs[(dir * B + n) * NT + t];
  }
#pragma unroll
  for (int s = 32; s > 0; s >>= 1)
    v += __shfl_down(v, s, 64);
  if (lane == 0) out[n] = v * (0.5f / (float)N);
}

extern "C" void kernel_launch(void* const* d_in, const int* in_sizes, int n_in,
                              void* d_out, int out_size, void* d_ws, size_t ws_size,
                              hipStream_t stream) {
  const float2* P1 = (const float2*)d_in[0];
  const float2* P2 = (const float2*)d_in[1];
  float* out = (float*)d_out;
  float* partial = (float*)d_ws;
  float* bs = partial + (size_t)NJ * 2 * B * N;

  chamfer_stage1<<<dim3(2 * B * NJ), S1B, 0, stream>>>(P1, P2, partial);
  chamfer_stage2<<<dim3(2 * B * NT), S2B, 0, stream>>>(P1, P2, partial, bs);
  chamfer_stage3<<<dim3(B), 64, 0, stream>>>(bs, out);
}

// Round 4
// 35.137 us; speedup vs baseline: 1.3761x; 1.3761x over previous
//
#include <hip/hip_runtime.h>
#include <hip/hip_bf16.h>
#include <math.h>

// Chamfer 2D, B=8, N=4096, fp32.
// Stage1 (R2 structure + TX=16 + min3): per (dir,n,c) block, LDS-broadcast
// database chunk as {-2y0,-2y1,|y|^2}; inner loop 2 j's/iter:
//   t0,t1 = 2 fma each; m = v_min3(m,t0,t1)  -> 2.5 instr slots per pair.
// Stage2: min over c, add |q|^2, sqrt, block-sum. Stage3: final tree sum.

#define B 8
#define N 4096
#define NJ 32
#define JC (N / NJ)      // 128 j's per stage1 block
#define S1B 256          // stage1 block (4 waves)
#define TX 16            // queries per thread: S1B*TX = 4096
#define NT 16            // i-tiles in stage2
#define S2B 256

// partial layout: [c][dir][n][i]
__global__ __launch_bounds__(S1B, 2) void chamfer_stage1(
    const float2* __restrict__ P1, const float2* __restrict__ P2,
    float* __restrict__ partial) {
  __shared__ float4 yb[JC];   // {-2*y0, -2*y1, |y|^2, 0}

  int b = blockIdx.x;
  int c = b % NJ; b /= NJ;
  int n = b % B;
  int dir = b / B;

  const float2* __restrict__ Q = dir ? P2 : P1;  // queries
  const float2* __restrict__ D = dir ? P1 : P2;  // database

  const float2* dbase = D + n * N + c * JC;
  for (int t = threadIdx.x; t < JC; t += S1B) {
    float2 p = dbase[t];
    yb[t] = make_float4(-2.0f * p.x, -2.0f * p.y,
                        fmaf(p.x, p.x, p.y * p.y), 0.0f);
  }
  __syncthreads();

  float qx[TX], qy[TX], m[TX];
  const float2* qbase = Q + n * N + threadIdx.x;
#pragma unroll
  for (int k = 0; k < TX; ++k) {
    float2 q = qbase[k * S1B];
    qx[k] = q.x; qy[k] = q.y;
    m[k] = INFINITY;
  }

  // 2 j's per iteration; wave-uniform LDS broadcast reads
#pragma unroll 2
  for (int j = 0; j < JC; j += 2) {
    float4 y0 = yb[j];
    float4 y1 = yb[j + 1];
#pragma unroll
    for (int k = 0; k < TX; ++k) {
      float t0 = fmaf(qx[k], y0.x, fmaf(qy[k], y0.y, y0.z));
      float t1 = fmaf(qx[k], y1.x, fmaf(qy[k], y1.y, y1.z));
      asm("v_min3_f32 %0, %0, %1, %2" : "+v"(m[k]) : "v"(t0), "v"(t1));
    }
  }

  float* __restrict__ dst =
      partial + (((size_t)c * 2 + dir) * B + n) * N + threadIdx.x;
#pragma unroll
  for (int k = 0; k < TX; ++k) dst[k * S1B] = m[k];
}

// grid: 2*B*NT blocks; min over c, add |q|^2, sqrt, block-sum.
__global__ __launch_bounds__(S2B) void chamfer_stage2(
    const float2* __restrict__ P1, const float2* __restrict__ P2,
    const float* __restrict__ partial, float* __restrict__ bs) {
  int b = blockIdx.x;
  int t = b % NT; b /= NT;
  int n = b % B;
  int dir = b / B;

  const float2* __restrict__ Q = dir ? P2 : P1;
  int i = t * S2B + threadIdx.x;

  float m = INFINITY;
  const float* __restrict__ pbase = partial + ((size_t)dir * B + n) * N + i;
#pragma unroll 8
  for (int c = 0; c < NJ; ++c)
    m = fminf(m, pbase[(size_t)c * 2 * B * N]);

  float2 q = Q[n * N + i];
  float d2 = m + fmaf(q.x, q.x, q.y * q.y);
  float sum = sqrtf(fmaxf(d2, 0.0f));

  __shared__ float red[S2B];
  red[threadIdx.x] = sum;
  __syncthreads();
  for (int s = S2B / 2; s > 0; s >>= 1) {
    if (threadIdx.x < s) red[threadIdx.x] += red[threadIdx.x + s];
    __syncthreads();
  }
  if (threadIdx.x == 0) bs[(dir * B + n) * NT + t] = red[0];
}

// grid: B blocks x 64 threads; reduce 2*NT=32 sums per n.
__global__ __launch_bounds__(64) void chamfer_stage3(
    const float* __restrict__ bs, float* __restrict__ out) {
  int n = blockIdx.x;
  int lane = threadIdx.x;
  float v = 0.0f;
  if (lane < 2 * NT) {
    int dir = lane / NT, t = lane % NT;
    v = bs[(dir * B + n) * NT + t];
  }
#pragma unroll
  for (int s = 32; s > 0; s >>= 1)
    v += __shfl_down(v, s, 64);
  if (lane == 0) out[n] = v * (0.5f / (float)N);
}

extern "C" void kernel_launch(void* const* d_in, const int* in_sizes, int n_in,
                              void* d_out, int out_size, void* d_ws, size_t ws_size,
                              hipStream_t stream) {
  const float2* P1 = (const float2*)d_in[0];
  const float2* P2 = (const float2*)d_in[1];
  float* out = (float*)d_out;
  float* partial = (float*)d_ws;
  float* bs = partial + (size_t)NJ * 2 * B * N;

  chamfer_stage1<<<dim3(2 * B * NJ), S1B, 0, stream>>>(P1, P2, partial);
  chamfer_stage2<<<dim3(2 * B * NT), S2B, 0, stream>>>(P1, P2, partial, bs);
  chamfer_stage3<<<dim3(B), 64, 0, stream>>>(bs, out);
}

// Round 5
// 31.334 us; speedup vs baseline: 1.5431x; 1.1214x over previous
//
#include <hip/hip_runtime.h>
#include <hip/hip_bf16.h>
#include <math.h>

// Chamfer 2D, B=8, N=4096, fp32. Two kernels.
// Stage1: per (dir,n,itile,c) block, min over j-chunk of (s_j - 2 x.y_j).
//   LDS SoA: axy (b128: -2x0,-2y0,-2x1,-2y1 per j-pair) + ssq (b64: |y|^2 pair).
//   Inner: 2 fma per j + fminf(fminf()) -> v_min3_f32 => 2.5 VALU slots/pair.
// Stage2: min over c, +|q|^2, sqrt, block-sum; LAST block per n (device-scope
//   atomic counter + threadfence) does the final 32-value reduce -> out[n].
//   Final reads use uint atomicAdd(ptr,0) coherent loads (XCD-safe, exact).

#define B 8
#define N 4096
#define NJ 16
#define NI 2
#define S1B 256
#define TX 8          // S1B*TX*NI = 4096
#define JC (N / NJ)   // 256 j's per stage1 block
#define JP (JC / 2)   // 128 j-pairs
#define NT 16
#define S2B 256

// ws layout: partial[NJ*2*B*N] | bs[2*B*NT] | cnt[B]
__global__ __launch_bounds__(S1B) void chamfer_stage1(
    const float2* __restrict__ P1, const float2* __restrict__ P2,
    float* __restrict__ partial, unsigned* __restrict__ cnt) {
  __shared__ float4 axy[JP];
  __shared__ float2 ssq[JP];

  if (blockIdx.x == 0 && threadIdx.x < B) cnt[threadIdx.x] = 0;  // per-launch reset

  int b = blockIdx.x;
  int c = b % NJ; b /= NJ;
  int itile = b % NI; b /= NI;
  int n = b % B;
  int dir = b / B;

  const float2* __restrict__ Q = dir ? P2 : P1;  // queries
  const float2* __restrict__ D = dir ? P1 : P2;  // database

  const float2* dbase = D + n * N + c * JC;
  for (int t = threadIdx.x; t < JP; t += S1B) {
    float2 p0 = dbase[2 * t];
    float2 p1 = dbase[2 * t + 1];
    axy[t] = make_float4(-2.f * p0.x, -2.f * p0.y, -2.f * p1.x, -2.f * p1.y);
    ssq[t] = make_float2(fmaf(p0.x, p0.x, p0.y * p0.y),
                         fmaf(p1.x, p1.x, p1.y * p1.y));
  }
  __syncthreads();

  float qx[TX], qy[TX], m[TX];
  const float2* qbase = Q + n * N + itile * (S1B * TX) + threadIdx.x;
#pragma unroll
  for (int k = 0; k < TX; ++k) {
    float2 q = qbase[k * S1B];
    qx[k] = q.x; qy[k] = q.y;
    m[k] = INFINITY;
  }

  // 2 j's per iteration; wave-uniform LDS broadcast (no bank conflicts)
#pragma unroll 4
  for (int jp = 0; jp < JP; ++jp) {
    float4 a = axy[jp];
    float2 s = ssq[jp];
#pragma unroll
    for (int k = 0; k < TX; ++k) {
      float t0 = fmaf(qx[k], a.x, fmaf(qy[k], a.y, s.x));
      float t1 = fmaf(qx[k], a.z, fmaf(qy[k], a.w, s.y));
      m[k] = fminf(fminf(m[k], t0), t1);   // fuses to v_min3_f32
    }
  }

  float* __restrict__ dst = partial + (((size_t)c * 2 + dir) * B + n) * N
                          + itile * (S1B * TX) + threadIdx.x;
#pragma unroll
  for (int k = 0; k < TX; ++k) dst[k * S1B] = m[k];
}

// grid: 2*B*NT blocks. Min over c, +|q|^2, sqrt, block-sum; last block per n
// does the final cross-block reduce and writes out[n].
__global__ __launch_bounds__(S2B) void chamfer_stage2(
    const float2* __restrict__ P1, const float2* __restrict__ P2,
    const float* __restrict__ partial, float* __restrict__ bs,
    unsigned* __restrict__ cnt, float* __restrict__ out) {
  int b = blockIdx.x;
  int t = b % NT; b /= NT;
  int n = b % B;
  int dir = b / B;

  const float2* __restrict__ Q = dir ? P2 : P1;
  int i = t * S2B + threadIdx.x;

  float m = INFINITY;
  const float* __restrict__ pbase = partial + ((size_t)dir * B + n) * N + i;
#pragma unroll
  for (int c = 0; c < NJ; ++c)
    m = fminf(m, pbase[(size_t)c * 2 * B * N]);

  float2 q = Q[n * N + i];
  float sum = sqrtf(fmaxf(m + fmaf(q.x, q.x, q.y * q.y), 0.0f));

  __shared__ float red[S2B];
  red[threadIdx.x] = sum;
  __syncthreads();
  for (int s = S2B / 2; s > 0; s >>= 1) {
    if (threadIdx.x < s) red[threadIdx.x] += red[threadIdx.x + s];
    __syncthreads();
  }

  __shared__ int last;
  if (threadIdx.x == 0) {
    bs[(dir * B + n) * NT + t] = red[0];
    __threadfence();                      // release: bs visible device-wide
    unsigned r = atomicAdd(&cnt[n], 1u);  // device-scope
    last = (r == 2 * NT - 1) ? 1 : 0;
  }
  __syncthreads();

  if (last && threadIdx.x < 64) {
    float v = 0.0f;
    if (threadIdx.x < 2 * NT) {
      int dd = threadIdx.x / NT, tt = threadIdx.x % NT;
      // coherent device-scope load (exact bits, deterministic)
      unsigned bits = atomicAdd(
          (unsigned*)&bs[(dd * B + n) * NT + tt], 0u);
      v = __uint_as_float(bits);
    }
#pragma unroll
    for (int s = 32; s > 0; s >>= 1)
      v += __shfl_down(v, s, 64);
    if (threadIdx.x == 0) out[n] = v * (0.5f / (float)N);
  }
}

extern "C" void kernel_launch(void* const* d_in, const int* in_sizes, int n_in,
                              void* d_out, int out_size, void* d_ws, size_t ws_size,
                              hipStream_t stream) {
  const float2* P1 = (const float2*)d_in[0];
  const float2* P2 = (const float2*)d_in[1];
  float* out = (float*)d_out;

  float* partial = (float*)d_ws;
  float* bs = partial + (size_t)NJ * 2 * B * N;
  unsigned* cnt = (unsigned*)(bs + 2 * B * NT);

  chamfer_stage1<<<dim3(2 * B * NI * NJ), S1B, 0, stream>>>(P1, P2, partial, cnt);
  chamfer_stage2<<<dim3(2 * B * NT), S2B, 0, stream>>>(P1, P2, partial, bs, cnt, out);
}